// Round 1
// baseline (1183.823 us; speedup 1.0000x reference)
//
#include <hip/hip_runtime.h>
#include <cstdio>
#include <cstdint>

// ---------------- types ----------------
typedef __bf16 bf16;
typedef __attribute__((ext_vector_type(8))) __bf16 bf16x8;
typedef __attribute__((ext_vector_type(4))) __bf16 bf16x4v;
typedef __attribute__((ext_vector_type(4))) float f32x4;

typedef const __attribute__((address_space(1))) unsigned int* as1_u32p;
typedef __attribute__((address_space(3))) unsigned int* as3_u32p;

__device__ __forceinline__ void gll16(const void* g, void* l) {
  // 16B-wide async global->LDS (lane i writes lds_base + 16*i)
  __builtin_amdgcn_global_load_lds((as1_u32p)g, (as3_u32p)l, 16, 0, 0);
}

// ---------------- problem constants ----------------
#define T_TOK 8192
#define DM 1024
#define DF 4096
#define CAP 2926          // ceil(1.25 * 8192*2 / 7)
#define CPAD 2944         // 23 * 128
#define ROUTED_ROWS 20608 // 7*2944
#define TOT_ROWS 28800    // +8192 shared rows
#define MT_ROUTED 161     // 7 * 23 M-tiles
#define MT_TOT 225        // + 64 shared M-tiles

// ---------------- workspace layout (bytes) ----------------
static constexpr size_t OFF_W1T = 0;                    // [8][4096][1024] bf16
static constexpr size_t OFF_W3T = 67108864;             // [8][4096][1024] bf16
static constexpr size_t OFF_W2T = 134217728;            // [8][1024][4096] bf16
static constexpr size_t OFF_HB  = 201326592;            // [8192][1024] bf16
static constexpr size_t OFF_HH  = 218103808;            // [28800][4096] bf16
static constexpr size_t OFF_TKE = 454033408;            // [2][8192] int
static constexpr size_t OFF_TKG = 454098944;            // [2][8192] float
static constexpr size_t OFF_STK = 454164480;            // [20608] int slot->token
static constexpr size_t OFF_SGT = 454246912;            // [20608] float slot->gate
static constexpr size_t OFF_CNT = 454329344;            // [8] int counters
static constexpr size_t WS_NEED = 454329600;

// ================= weight transpose + bf16 convert =================
// src: per-expert [R][C] fp32 (7 experts in srcE, expert 7 = srcS)
// dst: [8][C][R] bf16  (n-major so GEMM B-operand is k-contiguous)
__global__ __launch_bounds__(256) void prep_w(const float* __restrict__ srcE,
                                              const float* __restrict__ srcS,
                                              bf16* __restrict__ dst, int R, int C) {
  const int tilesPerE = (R >> 6) * (C >> 6);
  const int e = blockIdx.x / tilesPerE;
  const int ti = blockIdx.x % tilesPerE;
  const int ncTiles = C >> 6;
  const int tr = ti / ncTiles, tc = ti % ncTiles;
  const float* src = (e < 7) ? (srcE + (size_t)e * R * C) : srcS;
  __shared__ float tile[64][65];
  const int tid = threadIdx.x;
#pragma unroll
  for (int i = 0; i < 4; ++i) {
    int linear = (tid + 256 * i) * 4;
    int lr = linear >> 6, lc = linear & 63;
    float4 v = *(const float4*)(src + (size_t)(tr * 64 + lr) * C + tc * 64 + lc);
    tile[lr][lc] = v.x; tile[lr][lc + 1] = v.y; tile[lr][lc + 2] = v.z; tile[lr][lc + 3] = v.w;
  }
  __syncthreads();
  bf16* d = dst + (size_t)e * R * C;
#pragma unroll
  for (int i = 0; i < 4; ++i) {
    int linear = (tid + 256 * i) * 4;
    int lr = linear >> 6, lc = linear & 63; // dst row (=src col), dst col (=src row)
    bf16x4v o;
    o.x = (bf16)tile[lc + 0][lr]; o.y = (bf16)tile[lc + 1][lr];
    o.z = (bf16)tile[lc + 2][lr]; o.w = (bf16)tile[lc + 3][lr];
    *(bf16x4v*)(d + (size_t)(tc * 64 + lr) * R + tr * 64 + lc) = o;
  }
}

// ================= layernorm + router (fp64 stats/logits) =================
__global__ __launch_bounds__(256) void ln_router(const float* __restrict__ x,
                                                 const float* __restrict__ g,
                                                 const float* __restrict__ b,
                                                 const float* __restrict__ Wr,
                                                 bf16* __restrict__ hB,
                                                 int* __restrict__ tkE,
                                                 float* __restrict__ tkG) {
  const int t = blockIdx.x;
  const int tid = threadIdx.x;
  const int wave = tid >> 6, lane = tid & 63;
  const float4 xv = ((const float4*)(x + (size_t)t * DM))[tid];
  double s = (double)xv.x + (double)xv.y + (double)xv.z + (double)xv.w;
  double s2 = (double)xv.x * xv.x + (double)xv.y * xv.y + (double)xv.z * xv.z + (double)xv.w * xv.w;
#pragma unroll
  for (int off = 32; off > 0; off >>= 1) { s += __shfl_down(s, off); s2 += __shfl_down(s2, off); }
  __shared__ double red[2][4];
  __shared__ float muS, rsS;
  if (lane == 0) { red[0][wave] = s; red[1][wave] = s2; }
  __syncthreads();
  if (tid == 0) {
    double S = red[0][0] + red[0][1] + red[0][2] + red[0][3];
    double S2 = red[1][0] + red[1][1] + red[1][2] + red[1][3];
    double mu = S / 1024.0;
    double var = S2 / 1024.0 - mu * mu;
    muS = (float)mu;
    rsS = (float)(1.0 / sqrt(var + 1e-5));
  }
  __syncthreads();
  const float mu = muS, rs = rsS;
  const float4 gv = ((const float4*)g)[tid];
  const float4 bv = ((const float4*)b)[tid];
  float hv[4];
  hv[0] = (xv.x - mu) * rs * gv.x + bv.x;
  hv[1] = (xv.y - mu) * rs * gv.y + bv.y;
  hv[2] = (xv.z - mu) * rs * gv.z + bv.z;
  hv[3] = (xv.w - mu) * rs * gv.w + bv.w;
  bf16x4v hq; hq.x = (bf16)hv[0]; hq.y = (bf16)hv[1]; hq.z = (bf16)hv[2]; hq.w = (bf16)hv[3];
  ((bf16x4v*)(hB + (size_t)t * DM))[tid] = hq;
  // router partials (fp64 so top-2 selection is flip-proof)
  double p[7] = {0, 0, 0, 0, 0, 0, 0};
  const int d0 = tid * 4;
#pragma unroll
  for (int j = 0; j < 4; ++j) {
    const float* wr = Wr + (size_t)(d0 + j) * 7;
    const double hj = (double)hv[j];
#pragma unroll
    for (int e = 0; e < 7; ++e) p[e] += hj * (double)wr[e];
  }
#pragma unroll
  for (int off = 32; off > 0; off >>= 1)
#pragma unroll
    for (int e = 0; e < 7; ++e) p[e] += __shfl_down(p[e], off);
  __shared__ double plog[4][7];
  if (lane == 0)
#pragma unroll
    for (int e = 0; e < 7; ++e) plog[wave][e] = p[e];
  __syncthreads();
  if (tid == 0) {
    double L[7];
#pragma unroll
    for (int e = 0; e < 7; ++e) L[e] = plog[0][e] + plog[1][e] + plog[2][e] + plog[3][e];
    int i0 = 0;
    for (int e = 1; e < 7; ++e) if (L[e] > L[i0]) i0 = e;       // ties -> lowest idx (matches top_k)
    int i1 = -1;
    for (int e = 0; e < 7; ++e) { if (e == i0) continue; if (i1 < 0 || L[e] > L[i1]) i1 = e; }
    double g0 = 1.0 / (1.0 + exp(L[i1] - L[i0]));
    tkE[t] = i0; tkE[T_TOK + t] = i1;
    tkG[t] = (float)g0; tkG[T_TOK + t] = (float)(1.0 - g0);
  }
}

// ================= capacity slot assignment (phase k) =================
__global__ __launch_bounds__(256) void assign_phase(const int* __restrict__ tkE,
                                                    const float* __restrict__ tkG,
                                                    int k, int* __restrict__ counters,
                                                    int* __restrict__ slot_token,
                                                    float* __restrict__ slot_gate) {
  const int t = blockIdx.x * 256 + threadIdx.x;
  if (t >= T_TOK) return;
  const int e = tkE[k * T_TOK + t];
  const int pos = atomicAdd(&counters[e], 1);
  if (pos < CAP) {
    const int row = e * CPAD + pos;
    slot_token[row] = t;
    slot_gate[row] = tkG[k * T_TOK + t];
  }
}

// ================= GEMM13: hh = silu(A@W1) * (A@W3), grouped =================
__global__ __launch_bounds__(256, 2) void gemm13(const bf16* __restrict__ hB,
                                                 const bf16* __restrict__ W1t,
                                                 const bf16* __restrict__ W3t,
                                                 const int* __restrict__ slot_token,
                                                 const int* __restrict__ counters,
                                                 bf16* __restrict__ hh) {
  const int bid = blockIdx.x;
  const int tile_n = bid & 31;
  const int tile_m = bid >> 5;
  int e, count, tloc;
  if (tile_m >= MT_ROUTED) { e = 7; count = T_TOK; tloc = tile_m - MT_ROUTED; }
  else { e = tile_m / 23; tloc = tile_m - e * 23; int c = counters[e]; count = c > CAP ? CAP : c; }
  if (tloc * 128 >= count) return;

  const int tid = threadIdx.x;
  const int wave = tid >> 6, lane = tid & 63;
  const int wm = wave >> 1, wn = wave & 1;
  const int lr = lane >> 3;      // row within 8-row staging group
  const int lc = lane & 7;       // lds chunk
  const int gc = lc ^ lr;        // global chunk (XOR swizzle; r&7 == lr)
  const int rowbase = tile_m * 128;

  size_t aoff[4], boff[4];
#pragma unroll
  for (int j = 0; j < 4; ++j) {
    const int r = (j * 4 + wave) * 8 + lr;
    const int srow = rowbase + r;
    int tok;
    if (e == 7) tok = srow - ROUTED_ROWS;
    else { tok = slot_token[srow]; if (tok < 0) tok = 0; } // unused slot -> finite garbage, row-contained
    aoff[j] = (size_t)tok * (DM * 2) + (size_t)(gc * 16);
    boff[j] = (size_t)(tile_n * 128 + r) * (DM * 2) + (size_t)(gc * 16);
  }
  const char* Ag = (const char*)hB;
  const char* B1g = (const char*)(W1t + (size_t)e * DF * DM);
  const char* B3g = (const char*)(W3t + (size_t)e * DF * DM);

  __shared__ __align__(16) char sA[16384];
  __shared__ __align__(16) char sB1[16384];
  __shared__ __align__(16) char sB3[16384];

  const int quad = lane >> 4;
  const int fbase = (lane & 15) * 128 + ((quad ^ (lane & 7)) * 16); // swizzled frag addr, ks=0

  f32x4 acc1[4][4], acc3[4][4];
#pragma unroll
  for (int i = 0; i < 4; ++i)
#pragma unroll
    for (int j = 0; j < 4; ++j) { acc1[i][j] = {0.f, 0.f, 0.f, 0.f}; acc3[i][j] = {0.f, 0.f, 0.f, 0.f}; }

  for (int kt = 0; kt < 16; ++kt) {
    __syncthreads();
    const size_t kb = (size_t)kt * 128;
#pragma unroll
    for (int j = 0; j < 4; ++j) gll16(Ag + aoff[j] + kb, sA + (j * 4 + wave) * 1024);
#pragma unroll
    for (int j = 0; j < 4; ++j) gll16(B1g + boff[j] + kb, sB1 + (j * 4 + wave) * 1024);
#pragma unroll
    for (int j = 0; j < 4; ++j) gll16(B3g + boff[j] + kb, sB3 + (j * 4 + wave) * 1024);
    __syncthreads();
#pragma unroll
    for (int ks = 0; ks < 2; ++ks) {
      const int xo = ks ? 64 : 0; // chunk ^= 4 under swizzle
      bf16x8 af[4], b1f[4], b3f[4];
      const int ab = wm * 8192 + (fbase ^ xo);
      const int bb = wn * 8192 + (fbase ^ xo);
#pragma unroll
      for (int mi = 0; mi < 4; ++mi) af[mi] = *(const bf16x8*)(sA + ab + mi * 2048);
#pragma unroll
      for (int ni = 0; ni < 4; ++ni) {
        b1f[ni] = *(const bf16x8*)(sB1 + bb + ni * 2048);
        b3f[ni] = *(const bf16x8*)(sB3 + bb + ni * 2048);
      }
#pragma unroll
      for (int mi = 0; mi < 4; ++mi)
#pragma unroll
        for (int ni = 0; ni < 4; ++ni) {
          acc1[mi][ni] = __builtin_amdgcn_mfma_f32_16x16x32_bf16(af[mi], b1f[ni], acc1[mi][ni], 0, 0, 0);
          acc3[mi][ni] = __builtin_amdgcn_mfma_f32_16x16x32_bf16(af[mi], b3f[ni], acc3[mi][ni], 0, 0, 0);
        }
    }
  }
  // fused SwiGLU epilogue -> hh bf16
  const int col0 = tile_n * 128 + wn * 64 + (lane & 15);
  const int row0 = rowbase + wm * 64 + quad * 4;
#pragma unroll
  for (int mi = 0; mi < 4; ++mi)
#pragma unroll
    for (int r = 0; r < 4; ++r) {
      const int row = row0 + mi * 16 + r;
      bf16* dst = hh + (size_t)row * DF + col0;
#pragma unroll
      for (int ni = 0; ni < 4; ++ni) {
        const float a = acc1[mi][ni][r];
        const float b3 = acc3[mi][ni][r];
        const float v = (a / (1.f + __expf(-a))) * b3;
        dst[ni * 16] = (bf16)v;
      }
    }
}

// ================= GEMM2: out += gate * (hh @ W2), atomic combine =================
__global__ __launch_bounds__(256, 2) void gemm2k(const bf16* __restrict__ hh,
                                                 const bf16* __restrict__ W2t,
                                                 const int* __restrict__ slot_token,
                                                 const float* __restrict__ slot_gate,
                                                 const int* __restrict__ counters,
                                                 float* __restrict__ out) {
  const int bid = blockIdx.x;
  const int tile_n = bid & 7;
  const int tile_m = bid >> 3;
  int e, count, tloc;
  if (tile_m >= MT_ROUTED) { e = 7; count = T_TOK; tloc = tile_m - MT_ROUTED; }
  else { e = tile_m / 23; tloc = tile_m - e * 23; int c = counters[e]; count = c > CAP ? CAP : c; }
  if (tloc * 128 >= count) return;

  const int tid = threadIdx.x;
  const int wave = tid >> 6, lane = tid & 63;
  const int wm = wave >> 1, wn = wave & 1;
  const int lr = lane >> 3, lc = lane & 7;
  const int gc = lc ^ lr;
  const int rowbase = tile_m * 128;

  size_t aoff[4], boff[4];
#pragma unroll
  for (int j = 0; j < 4; ++j) {
    const int r = (j * 4 + wave) * 8 + lr;
    aoff[j] = (size_t)(rowbase + r) * (DF * 2) + (size_t)(gc * 16);
    boff[j] = (size_t)(tile_n * 128 + r) * (DF * 2) + (size_t)(gc * 16);
  }
  const char* Ag = (const char*)hh;
  const char* Bg = (const char*)(W2t + (size_t)e * DM * DF);

  __shared__ __align__(16) char sA[16384];
  __shared__ __align__(16) char sB[16384];

  const int quad = lane >> 4;
  const int fbase = (lane & 15) * 128 + ((quad ^ (lane & 7)) * 16);

  f32x4 acc[4][4];
#pragma unroll
  for (int i = 0; i < 4; ++i)
#pragma unroll
    for (int j = 0; j < 4; ++j) acc[i][j] = {0.f, 0.f, 0.f, 0.f};

  for (int kt = 0; kt < 64; ++kt) {
    __syncthreads();
    const size_t kb = (size_t)kt * 128;
#pragma unroll
    for (int j = 0; j < 4; ++j) gll16(Ag + aoff[j] + kb, sA + (j * 4 + wave) * 1024);
#pragma unroll
    for (int j = 0; j < 4; ++j) gll16(Bg + boff[j] + kb, sB + (j * 4 + wave) * 1024);
    __syncthreads();
#pragma unroll
    for (int ks = 0; ks < 2; ++ks) {
      const int xo = ks ? 64 : 0;
      bf16x8 af[4], bf[4];
      const int ab = wm * 8192 + (fbase ^ xo);
      const int bb = wn * 8192 + (fbase ^ xo);
#pragma unroll
      for (int mi = 0; mi < 4; ++mi) af[mi] = *(const bf16x8*)(sA + ab + mi * 2048);
#pragma unroll
      for (int ni = 0; ni < 4; ++ni) bf[ni] = *(const bf16x8*)(sB + bb + ni * 2048);
#pragma unroll
      for (int mi = 0; mi < 4; ++mi)
#pragma unroll
        for (int ni = 0; ni < 4; ++ni)
          acc[mi][ni] = __builtin_amdgcn_mfma_f32_16x16x32_bf16(af[mi], bf[ni], acc[mi][ni], 0, 0, 0);
    }
  }
  // gate-scaled atomic combine into out (<=3 adds per element)
  const int col0 = tile_n * 128 + wn * 64 + (lane & 15);
  const int row0 = rowbase + wm * 64 + quad * 4;
#pragma unroll
  for (int mi = 0; mi < 4; ++mi)
#pragma unroll
    for (int r = 0; r < 4; ++r) {
      const int slot_row = row0 + mi * 16 + r;
      int tok; float gate;
      if (slot_row >= ROUTED_ROWS) { tok = slot_row - ROUTED_ROWS; gate = 1.f; }
      else {
        tok = slot_token[slot_row];
        if (tok < 0) continue; // unused capacity slot
        gate = slot_gate[slot_row];
      }
      float* dst = out + (size_t)tok * DM + col0;
#pragma unroll
      for (int ni = 0; ni < 4; ++ni) atomicAdd(dst + ni * 16, gate * acc[mi][ni][r]);
    }
}

// ================= host launch =================
extern "C" void kernel_launch(void* const* d_in, const int* in_sizes, int n_in,
                              void* d_out, int out_size, void* d_ws, size_t ws_size,
                              hipStream_t stream) {
  (void)in_sizes; (void)n_in;
  const float* x = (const float*)d_in[0];
  const float* lng = (const float*)d_in[1];
  const float* lnb = (const float*)d_in[2];
  const float* Wr = (const float*)d_in[3];
  const float* W1 = (const float*)d_in[4];
  const float* W3 = (const float*)d_in[5];
  const float* W2 = (const float*)d_in[6];
  const float* W1s = (const float*)d_in[7];
  const float* W3s = (const float*)d_in[8];
  const float* W2s = (const float*)d_in[9];
  float* out = (float*)d_out;
  char* ws = (char*)d_ws;

  if (ws_size < WS_NEED) {
    fprintf(stderr, "kernel_launch: ws_size=%zu < needed %zu — aborting launches\n",
            ws_size, (size_t)WS_NEED);
    return;
  }

  bf16* W1t = (bf16*)(ws + OFF_W1T);
  bf16* W3t = (bf16*)(ws + OFF_W3T);
  bf16* W2t = (bf16*)(ws + OFF_W2T);
  bf16* hB = (bf16*)(ws + OFF_HB);
  bf16* hh = (bf16*)(ws + OFF_HH);
  int* tkE = (int*)(ws + OFF_TKE);
  float* tkG = (float*)(ws + OFF_TKG);
  int* stk = (int*)(ws + OFF_STK);
  float* sgt = (float*)(ws + OFF_SGT);
  int* cnt = (int*)(ws + OFF_CNT);

  hipMemsetAsync(cnt, 0, 8 * sizeof(int), stream);
  hipMemsetAsync(stk, 0xFF, ROUTED_ROWS * sizeof(int), stream); // -1
  hipMemsetAsync(out, 0, (size_t)out_size * sizeof(float), stream);

  prep_w<<<8192, 256, 0, stream>>>(W1, W1s, W1t, DM, DF);
  prep_w<<<8192, 256, 0, stream>>>(W3, W3s, W3t, DM, DF);
  prep_w<<<8192, 256, 0, stream>>>(W2, W2s, W2t, DF, DM);

  ln_router<<<T_TOK, 256, 0, stream>>>(x, lng, lnb, Wr, hB, tkE, tkG);
  assign_phase<<<32, 256, 0, stream>>>(tkE, tkG, 0, cnt, stk, sgt);
  assign_phase<<<32, 256, 0, stream>>>(tkE, tkG, 1, cnt, stk, sgt);

  gemm13<<<MT_TOT * 32, 256, 0, stream>>>(hB, W1t, W3t, stk, cnt, hh);
  gemm2k<<<MT_TOT * 8, 256, 0, stream>>>(hh, W2t, stk, sgt, cnt, out);
}

// Round 2
// 1149.640 us; speedup vs baseline: 1.0297x; 1.0297x over previous
//
#include <hip/hip_runtime.h>
#include <cstdio>
#include <cstdint>

// ---------------- types ----------------
typedef __bf16 bf16;
typedef __attribute__((ext_vector_type(8))) __bf16 bf16x8;
typedef __attribute__((ext_vector_type(4))) __bf16 bf16x4v;
typedef __attribute__((ext_vector_type(4))) float f32x4;

typedef const __attribute__((address_space(1))) unsigned int* as1_u32p;
typedef __attribute__((address_space(3))) unsigned int* as3_u32p;

__device__ __forceinline__ void gll16(const void* g, void* l) {
  // 16B-wide async global->LDS (lane i writes lds_base + 16*i)
  __builtin_amdgcn_global_load_lds((as1_u32p)g, (as3_u32p)l, 16, 0, 0);
}

// ---------------- problem constants ----------------
#define T_TOK 8192
#define DM 1024
#define DF 4096
#define CAP 2926          // ceil(1.25 * 8192*2 / 7)
#define CPAD 2944         // 23 * 128
#define ROUTED_ROWS 20608 // 7*2944
#define TOT_ROWS 28800    // +8192 shared rows
#define MT_ROUTED 161     // 7 * 23 M-tiles
#define MT_TOT 225        // + 64 shared M-tiles

// ---------------- workspace layout (bytes) ----------------
// ye (fp32 [28800][1024] = 115.3 MB) is overlaid on W1T+W3T (134.2 MB):
// W1t/W3t are dead after gemm13; gemm2k writes ye there; prep_w rewrites
// them at the start of every call. No footprint growth.
static constexpr size_t OFF_W1T = 0;                    // [8][4096][1024] bf16
static constexpr size_t OFF_W3T = 67108864;             // [8][4096][1024] bf16
static constexpr size_t OFF_YE  = 0;                    // [28800][1024] f32 (overlay)
static constexpr size_t OFF_W2T = 134217728;            // [8][1024][4096] bf16
static constexpr size_t OFF_HB  = 201326592;            // [8192][1024] bf16
static constexpr size_t OFF_HH  = 218103808;            // [28800][4096] bf16
static constexpr size_t OFF_TKE = 454033408;            // [2][8192] int
static constexpr size_t OFF_TKG = 454098944;            // [2][8192] float
static constexpr size_t OFF_STK = 454164480;            // [20608] int slot->token
static constexpr size_t OFF_TKS = 454246912;            // [2][8192] int token->slot
static constexpr size_t OFF_CNT = 454329344;            // [8] int counters
static constexpr size_t WS_NEED = 454329600;

// ================= weight transpose + bf16 convert =================
__global__ __launch_bounds__(256) void prep_w(const float* __restrict__ srcE,
                                              const float* __restrict__ srcS,
                                              bf16* __restrict__ dst, int R, int C) {
  const int tilesPerE = (R >> 6) * (C >> 6);
  const int e = blockIdx.x / tilesPerE;
  const int ti = blockIdx.x % tilesPerE;
  const int ncTiles = C >> 6;
  const int tr = ti / ncTiles, tc = ti % ncTiles;
  const float* src = (e < 7) ? (srcE + (size_t)e * R * C) : srcS;
  __shared__ float tile[64][65];
  const int tid = threadIdx.x;
#pragma unroll
  for (int i = 0; i < 4; ++i) {
    int linear = (tid + 256 * i) * 4;
    int lr = linear >> 6, lc = linear & 63;
    float4 v = *(const float4*)(src + (size_t)(tr * 64 + lr) * C + tc * 64 + lc);
    tile[lr][lc] = v.x; tile[lr][lc + 1] = v.y; tile[lr][lc + 2] = v.z; tile[lr][lc + 3] = v.w;
  }
  __syncthreads();
  bf16* d = dst + (size_t)e * R * C;
#pragma unroll
  for (int i = 0; i < 4; ++i) {
    int linear = (tid + 256 * i) * 4;
    int lr = linear >> 6, lc = linear & 63;
    bf16x4v o;
    o.x = (bf16)tile[lc + 0][lr]; o.y = (bf16)tile[lc + 1][lr];
    o.z = (bf16)tile[lc + 2][lr]; o.w = (bf16)tile[lc + 3][lr];
    *(bf16x4v*)(d + (size_t)(tc * 64 + lr) * R + tr * 64 + lc) = o;
  }
}

// ================= layernorm + router (fp64 stats/logits) =================
__global__ __launch_bounds__(256) void ln_router(const float* __restrict__ x,
                                                 const float* __restrict__ g,
                                                 const float* __restrict__ b,
                                                 const float* __restrict__ Wr,
                                                 bf16* __restrict__ hB,
                                                 int* __restrict__ tkE,
                                                 float* __restrict__ tkG) {
  const int t = blockIdx.x;
  const int tid = threadIdx.x;
  const int wave = tid >> 6, lane = tid & 63;
  const float4 xv = ((const float4*)(x + (size_t)t * DM))[tid];
  double s = (double)xv.x + (double)xv.y + (double)xv.z + (double)xv.w;
  double s2 = (double)xv.x * xv.x + (double)xv.y * xv.y + (double)xv.z * xv.z + (double)xv.w * xv.w;
#pragma unroll
  for (int off = 32; off > 0; off >>= 1) { s += __shfl_down(s, off); s2 += __shfl_down(s2, off); }
  __shared__ double red[2][4];
  __shared__ float muS, rsS;
  if (lane == 0) { red[0][wave] = s; red[1][wave] = s2; }
  __syncthreads();
  if (tid == 0) {
    double S = red[0][0] + red[0][1] + red[0][2] + red[0][3];
    double S2 = red[1][0] + red[1][1] + red[1][2] + red[1][3];
    double mu = S / 1024.0;
    double var = S2 / 1024.0 - mu * mu;
    muS = (float)mu;
    rsS = (float)(1.0 / sqrt(var + 1e-5));
  }
  __syncthreads();
  const float mu = muS, rs = rsS;
  const float4 gv = ((const float4*)g)[tid];
  const float4 bv = ((const float4*)b)[tid];
  float hv[4];
  hv[0] = (xv.x - mu) * rs * gv.x + bv.x;
  hv[1] = (xv.y - mu) * rs * gv.y + bv.y;
  hv[2] = (xv.z - mu) * rs * gv.z + bv.z;
  hv[3] = (xv.w - mu) * rs * gv.w + bv.w;
  bf16x4v hq; hq.x = (bf16)hv[0]; hq.y = (bf16)hv[1]; hq.z = (bf16)hv[2]; hq.w = (bf16)hv[3];
  ((bf16x4v*)(hB + (size_t)t * DM))[tid] = hq;
  double p[7] = {0, 0, 0, 0, 0, 0, 0};
  const int d0 = tid * 4;
#pragma unroll
  for (int j = 0; j < 4; ++j) {
    const float* wr = Wr + (size_t)(d0 + j) * 7;
    const double hj = (double)hv[j];
#pragma unroll
    for (int e = 0; e < 7; ++e) p[e] += hj * (double)wr[e];
  }
#pragma unroll
  for (int off = 32; off > 0; off >>= 1)
#pragma unroll
    for (int e = 0; e < 7; ++e) p[e] += __shfl_down(p[e], off);
  __shared__ double plog[4][7];
  if (lane == 0)
#pragma unroll
    for (int e = 0; e < 7; ++e) plog[wave][e] = p[e];
  __syncthreads();
  if (tid == 0) {
    double L[7];
#pragma unroll
    for (int e = 0; e < 7; ++e) L[e] = plog[0][e] + plog[1][e] + plog[2][e] + plog[3][e];
    int i0 = 0;
    for (int e = 1; e < 7; ++e) if (L[e] > L[i0]) i0 = e;
    int i1 = -1;
    for (int e = 0; e < 7; ++e) { if (e == i0) continue; if (i1 < 0 || L[e] > L[i1]) i1 = e; }
    double g0 = 1.0 / (1.0 + exp(L[i1] - L[i0]));
    tkE[t] = i0; tkE[T_TOK + t] = i1;
    tkG[t] = (float)g0; tkG[T_TOK + t] = (float)(1.0 - g0);
  }
}

// ================= capacity slot assignment (phase k) =================
__global__ __launch_bounds__(256) void assign_phase(const int* __restrict__ tkE,
                                                    const float* __restrict__ tkG,
                                                    int k, int* __restrict__ counters,
                                                    int* __restrict__ slot_token,
                                                    int* __restrict__ tok_slot) {
  const int t = blockIdx.x * 256 + threadIdx.x;
  if (t >= T_TOK) return;
  const int e = tkE[k * T_TOK + t];
  const int pos = atomicAdd(&counters[e], 1);
  if (pos < CAP) {
    const int row = e * CPAD + pos;
    slot_token[row] = t;
    tok_slot[k * T_TOK + t] = row;
  } else {
    tok_slot[k * T_TOK + t] = -1; // dropped
  }
}

// ================= GEMM13: hh = silu(A@W1) * (A@W3), grouped =================
__global__ __launch_bounds__(256, 2) void gemm13(const bf16* __restrict__ hB,
                                                 const bf16* __restrict__ W1t,
                                                 const bf16* __restrict__ W3t,
                                                 const int* __restrict__ slot_token,
                                                 const int* __restrict__ counters,
                                                 bf16* __restrict__ hh) {
  const int bid = blockIdx.x;
  const int tile_n = bid & 31;
  const int tile_m = bid >> 5;
  int e, count, tloc;
  if (tile_m >= MT_ROUTED) { e = 7; count = T_TOK; tloc = tile_m - MT_ROUTED; }
  else { e = tile_m / 23; tloc = tile_m - e * 23; int c = counters[e]; count = c > CAP ? CAP : c; }
  if (tloc * 128 >= count) return;

  const int tid = threadIdx.x;
  const int wave = tid >> 6, lane = tid & 63;
  const int wm = wave >> 1, wn = wave & 1;
  const int lr = lane >> 3;
  const int lc = lane & 7;
  const int gc = lc ^ lr; // XOR swizzle
  const int rowbase = tile_m * 128;

  size_t aoff[4], boff[4];
#pragma unroll
  for (int j = 0; j < 4; ++j) {
    const int r = (j * 4 + wave) * 8 + lr;
    const int srow = rowbase + r;
    int tok;
    if (e == 7) tok = srow - ROUTED_ROWS;
    else { tok = slot_token[srow]; if (tok < 0) tok = 0; }
    aoff[j] = (size_t)tok * (DM * 2) + (size_t)(gc * 16);
    boff[j] = (size_t)(tile_n * 128 + r) * (DM * 2) + (size_t)(gc * 16);
  }
  const char* Ag = (const char*)hB;
  const char* B1g = (const char*)(W1t + (size_t)e * DF * DM);
  const char* B3g = (const char*)(W3t + (size_t)e * DF * DM);

  __shared__ __align__(16) char sA[16384];
  __shared__ __align__(16) char sB1[16384];
  __shared__ __align__(16) char sB3[16384];

  const int quad = lane >> 4;
  const int fbase = (lane & 15) * 128 + ((quad ^ (lane & 7)) * 16);

  f32x4 acc1[4][4], acc3[4][4];
#pragma unroll
  for (int i = 0; i < 4; ++i)
#pragma unroll
    for (int j = 0; j < 4; ++j) { acc1[i][j] = {0.f, 0.f, 0.f, 0.f}; acc3[i][j] = {0.f, 0.f, 0.f, 0.f}; }

  for (int kt = 0; kt < 16; ++kt) {
    __syncthreads();
    const size_t kb = (size_t)kt * 128;
#pragma unroll
    for (int j = 0; j < 4; ++j) gll16(Ag + aoff[j] + kb, sA + (j * 4 + wave) * 1024);
#pragma unroll
    for (int j = 0; j < 4; ++j) gll16(B1g + boff[j] + kb, sB1 + (j * 4 + wave) * 1024);
#pragma unroll
    for (int j = 0; j < 4; ++j) gll16(B3g + boff[j] + kb, sB3 + (j * 4 + wave) * 1024);
    __syncthreads();
#pragma unroll
    for (int ks = 0; ks < 2; ++ks) {
      const int xo = ks ? 64 : 0;
      bf16x8 af[4], b1f[4], b3f[4];
      const int ab = wm * 8192 + (fbase ^ xo);
      const int bb = wn * 8192 + (fbase ^ xo);
#pragma unroll
      for (int mi = 0; mi < 4; ++mi) af[mi] = *(const bf16x8*)(sA + ab + mi * 2048);
#pragma unroll
      for (int ni = 0; ni < 4; ++ni) {
        b1f[ni] = *(const bf16x8*)(sB1 + bb + ni * 2048);
        b3f[ni] = *(const bf16x8*)(sB3 + bb + ni * 2048);
      }
#pragma unroll
      for (int mi = 0; mi < 4; ++mi)
#pragma unroll
        for (int ni = 0; ni < 4; ++ni) {
          acc1[mi][ni] = __builtin_amdgcn_mfma_f32_16x16x32_bf16(af[mi], b1f[ni], acc1[mi][ni], 0, 0, 0);
          acc3[mi][ni] = __builtin_amdgcn_mfma_f32_16x16x32_bf16(af[mi], b3f[ni], acc3[mi][ni], 0, 0, 0);
        }
    }
  }
  const int col0 = tile_n * 128 + wn * 64 + (lane & 15);
  const int row0 = rowbase + wm * 64 + quad * 4;
#pragma unroll
  for (int mi = 0; mi < 4; ++mi)
#pragma unroll
    for (int r = 0; r < 4; ++r) {
      const int row = row0 + mi * 16 + r;
      bf16* dst = hh + (size_t)row * DF + col0;
#pragma unroll
      for (int ni = 0; ni < 4; ++ni) {
        const float a = acc1[mi][ni][r];
        const float b3 = acc3[mi][ni][r];
        const float v = (a / (1.f + __expf(-a))) * b3;
        dst[ni * 16] = (bf16)v;
      }
    }
}

// ================= GEMM2: ye[slot] = hh @ W2 (no atomics) =================
// Grid swizzle: bid = ((mgrp*8 + n) << 3) | x, tile_m = mgrp*8 + x.
// XCD = bid%8 = tile_m%8 (round-robin heuristic): all 8 n-tiles of one
// m-tile are consecutive on one XCD -> A strip read once into its L2.
__global__ __launch_bounds__(256, 2) void gemm2k(const bf16* __restrict__ hh,
                                                 const bf16* __restrict__ W2t,
                                                 const int* __restrict__ counters,
                                                 float* __restrict__ ye) {
  const int bid = blockIdx.x;
  const int x = bid & 7;
  const int q = bid >> 3;
  const int tile_n = q & 7;
  const int tile_m = (q >> 3) * 8 + x;
  if (tile_m >= MT_TOT) return;
  int e, count, tloc;
  if (tile_m >= MT_ROUTED) { e = 7; count = T_TOK; tloc = tile_m - MT_ROUTED; }
  else { e = tile_m / 23; tloc = tile_m - e * 23; int c = counters[e]; count = c > CAP ? CAP : c; }
  if (tloc * 128 >= count) return;

  const int tid = threadIdx.x;
  const int wave = tid >> 6, lane = tid & 63;
  const int wm = wave >> 1, wn = wave & 1;
  const int lr = lane >> 3, lc = lane & 7;
  const int gc = lc ^ lr;
  const int rowbase = tile_m * 128;

  size_t aoff[4], boff[4];
#pragma unroll
  for (int j = 0; j < 4; ++j) {
    const int r = (j * 4 + wave) * 8 + lr;
    aoff[j] = (size_t)(rowbase + r) * (DF * 2) + (size_t)(gc * 16);
    boff[j] = (size_t)(tile_n * 128 + r) * (DF * 2) + (size_t)(gc * 16);
  }
  const char* Ag = (const char*)hh;
  const char* Bg = (const char*)(W2t + (size_t)e * DM * DF);

  __shared__ __align__(16) char sA[16384];
  __shared__ __align__(16) char sB[16384];

  const int quad = lane >> 4;
  const int fbase = (lane & 15) * 128 + ((quad ^ (lane & 7)) * 16);

  f32x4 acc[4][4];
#pragma unroll
  for (int i = 0; i < 4; ++i)
#pragma unroll
    for (int j = 0; j < 4; ++j) acc[i][j] = {0.f, 0.f, 0.f, 0.f};

  for (int kt = 0; kt < 64; ++kt) {
    __syncthreads();
    const size_t kb = (size_t)kt * 128;
#pragma unroll
    for (int j = 0; j < 4; ++j) gll16(Ag + aoff[j] + kb, sA + (j * 4 + wave) * 1024);
#pragma unroll
    for (int j = 0; j < 4; ++j) gll16(Bg + boff[j] + kb, sB + (j * 4 + wave) * 1024);
    __syncthreads();
#pragma unroll
    for (int ks = 0; ks < 2; ++ks) {
      const int xo = ks ? 64 : 0;
      bf16x8 af[4], bfr[4];
      const int ab = wm * 8192 + (fbase ^ xo);
      const int bb = wn * 8192 + (fbase ^ xo);
#pragma unroll
      for (int mi = 0; mi < 4; ++mi) af[mi] = *(const bf16x8*)(sA + ab + mi * 2048);
#pragma unroll
      for (int ni = 0; ni < 4; ++ni) bfr[ni] = *(const bf16x8*)(sB + bb + ni * 2048);
#pragma unroll
      for (int mi = 0; mi < 4; ++mi)
#pragma unroll
        for (int ni = 0; ni < 4; ++ni)
          acc[mi][ni] = __builtin_amdgcn_mfma_f32_16x16x32_bf16(af[mi], bfr[ni], acc[mi][ni], 0, 0, 0);
    }
  }
  // plain fp32 stores into ye (gate applied in combine)
  const int col0 = tile_n * 128 + wn * 64 + (lane & 15);
  const int row0 = rowbase + wm * 64 + quad * 4;
#pragma unroll
  for (int mi = 0; mi < 4; ++mi)
#pragma unroll
    for (int r = 0; r < 4; ++r) {
      const int row = row0 + mi * 16 + r;
      float* dst = ye + (size_t)row * DM + col0;
#pragma unroll
      for (int ni = 0; ni < 4; ++ni) dst[ni * 16] = acc[mi][ni][r];
    }
}

// ================= combine: out[t] = g0*ye[s0] + g1*ye[s1] + ye[shared] =====
__global__ __launch_bounds__(256) void combine(const float* __restrict__ ye,
                                               const int* __restrict__ tok_slot,
                                               const float* __restrict__ tkG,
                                               float* __restrict__ out) {
  const int t = blockIdx.x;
  const int tid = threadIdx.x;
  const int s0 = tok_slot[t], s1 = tok_slot[T_TOK + t];
  const float g0 = tkG[t], g1 = tkG[T_TOK + t];
  float4 v = ((const float4*)(ye + (size_t)(ROUTED_ROWS + t) * DM))[tid];
  if (s0 >= 0) {
    float4 a = ((const float4*)(ye + (size_t)s0 * DM))[tid];
    v.x += g0 * a.x; v.y += g0 * a.y; v.z += g0 * a.z; v.w += g0 * a.w;
  }
  if (s1 >= 0) {
    float4 a = ((const float4*)(ye + (size_t)s1 * DM))[tid];
    v.x += g1 * a.x; v.y += g1 * a.y; v.z += g1 * a.z; v.w += g1 * a.w;
  }
  ((float4*)(out + (size_t)t * DM))[tid] = v;
}

// ================= host launch =================
extern "C" void kernel_launch(void* const* d_in, const int* in_sizes, int n_in,
                              void* d_out, int out_size, void* d_ws, size_t ws_size,
                              hipStream_t stream) {
  (void)in_sizes; (void)n_in; (void)out_size;
  const float* x = (const float*)d_in[0];
  const float* lng = (const float*)d_in[1];
  const float* lnb = (const float*)d_in[2];
  const float* Wr = (const float*)d_in[3];
  const float* W1 = (const float*)d_in[4];
  const float* W3 = (const float*)d_in[5];
  const float* W2 = (const float*)d_in[6];
  const float* W1s = (const float*)d_in[7];
  const float* W3s = (const float*)d_in[8];
  const float* W2s = (const float*)d_in[9];
  float* out = (float*)d_out;
  char* ws = (char*)d_ws;

  if (ws_size < WS_NEED) {
    fprintf(stderr, "kernel_launch: ws_size=%zu < needed %zu — aborting launches\n",
            ws_size, (size_t)WS_NEED);
    return;
  }

  bf16* W1t = (bf16*)(ws + OFF_W1T);
  bf16* W3t = (bf16*)(ws + OFF_W3T);
  bf16* W2t = (bf16*)(ws + OFF_W2T);
  float* ye = (float*)(ws + OFF_YE); // overlays W1t/W3t after gemm13
  bf16* hB = (bf16*)(ws + OFF_HB);
  bf16* hh = (bf16*)(ws + OFF_HH);
  int* tkE = (int*)(ws + OFF_TKE);
  float* tkG = (float*)(ws + OFF_TKG);
  int* stk = (int*)(ws + OFF_STK);
  int* tks = (int*)(ws + OFF_TKS);
  int* cnt = (int*)(ws + OFF_CNT);

  hipMemsetAsync(cnt, 0, 8 * sizeof(int), stream);
  hipMemsetAsync(stk, 0xFF, ROUTED_ROWS * sizeof(int), stream); // -1

  prep_w<<<8192, 256, 0, stream>>>(W1, W1s, W1t, DM, DF);
  prep_w<<<8192, 256, 0, stream>>>(W3, W3s, W3t, DM, DF);
  prep_w<<<8192, 256, 0, stream>>>(W2, W2s, W2t, DF, DM);

  ln_router<<<T_TOK, 256, 0, stream>>>(x, lng, lnb, Wr, hB, tkE, tkG);
  assign_phase<<<32, 256, 0, stream>>>(tkE, tkG, 0, cnt, stk, tks);
  assign_phase<<<32, 256, 0, stream>>>(tkE, tkG, 1, cnt, stk, tks);

  gemm13<<<MT_TOT * 32, 256, 0, stream>>>(hB, W1t, W3t, stk, cnt, hh);
  // swizzled grid: 29 mgrps * 8 n-tiles * 8 xcd-slots
  gemm2k<<<29 * 8 * 8, 256, 0, stream>>>(hh, W2t, cnt, ye);
  combine<<<T_TOK, 256, 0, stream>>>(ye, tks, tkG, out);
}